// Round 13
// baseline (253.689 us; speedup 1.0000x reference)
//
#include <hip/hip_runtime.h>
#include <math.h>

#define NXY    192
#define CELLS  (NXY*NXY)
#define NBATCH 4
#define NSTEPS 256
#define TCH    8                  // steps per chunk (= halo radius)
#define NCHUNK (NSTEPS/TCH)       // 32
#define TPB    512                // 8 waves -> 2 waves/SIMD
#define NW     8
#define RPL    3                  // rows per wave (24-row window / 8 waves)
#define OUTR   6                  // out rows per tile
#define NBLKS  256                // 32 row-tiles x 2 col-tiles x 4 batches
// in-tile 128 cols x 24 rows; out-tile 96 cols x 6 rows (window rows [9,15))

// workspace layout (float offsets)
#define K3_OFF (16*CELLS)
#define Q_OFF  (K3_OFF + CELLS)
#define I_OFF  (Q_OFF + CELLS)

typedef float v2f __attribute__((ext_vector_type(2)));

__device__ __forceinline__ float dpp_up1(float v) {   // lane i <- lane i-1
    int r = __builtin_amdgcn_update_dpp(0, __builtin_bit_cast(int, v),
                                        0x138, 0xf, 0xf, true); // wave_shr:1
    return __builtin_bit_cast(float, r);
}
__device__ __forceinline__ float dpp_dn1(float v) {   // lane i <- lane i+1
    int r = __builtin_amdgcn_update_dpp(0, __builtin_bit_cast(int, v),
                                        0x130, 0xf, 0xf, true); // wave_shl:1
    return __builtin_bit_cast(float, r);
}

__device__ __forceinline__ float pml_prof(int i) {
    int t;
    if (i <= 20)            t = 20 - i;
    else if (i >= NXY - 21) t = i - (NXY - 21);
    else                    return 0.0f;
    float u  = (float)t * 0.05f;
    float u2 = u * u;
    return 3.0f * u2 * u2;
}

__global__ void setup_k(const float* __restrict__ rho, float* __restrict__ ws) {
    int idx    = blockIdx.x * blockDim.x + threadIdx.x;
    int stride = gridDim.x * blockDim.x;
    for (int k = idx; k < 8 * CELLS; k += stride) ws[k] = 0.0f;  // parity-0 state
    const float IH2 = (float)(1.0 / (2.01 * 2.01));
    for (int k = idx; k < CELLS; k += stride) {
        int i = k / NXY, j = k % NXY;
        float r0 = rho[k];
        float ru = (i > 0)       ? rho[k - NXY] : 0.0f;
        float rd = (i < NXY - 1) ? rho[k + NXY] : 0.0f;
        float rl = (j > 0)       ? rho[k - 1]   : 0.0f;
        float rr2 = (j < NXY - 1) ? rho[k + 1]  : 0.0f;
        float lpf = 0.5f * r0 + 0.125f * ((ru + rd) + (rl + rr2));
        float p   = 0.5f * (1.0f + tanhf(100.0f * (lpf - 0.5f)));
        float c   = 1.0f - 0.1f * p;
        float c2h = c * c * IH2;
        float bx = pml_prof(i), by = pml_prof(j);
        float bb = sqrtf(bx * bx + by * by);
        float a1 = 1.0f / (1.0f + 0.5f * bb);
        ws[K3_OFF + k] = a1 * c2h;         // K
        ws[Q_OFF  + k] = 1.0f - 2.0f * a1; // Q
    }
    if (idx < 12) ws[I_OFF + idx] = 0.0f;
}

__global__ __launch_bounds__(TPB, 1)
void chunk_k(const float* __restrict__ x, float* __restrict__ ws, int chunk) {
    int blk = blockIdx.x;
    int b  = blk / 64;                // batch
    int r_ = blk % 64;
    int bi = r_ >> 1, cj = r_ & 1;    // 32 row-tiles x 2 col-tiles
    int I0 = OUTR * bi - 9;           // window row origin (24 rows)
    int J0 = 96 * cj - 16;            // window col origin (128 cols)
    int t  = threadIdx.x;
    int w  = t >> 6;                  // wave 0..7, owns window rows [3w,3w+3)
    int l  = t & 63;                  // lane: local cols 2l, 2l+1
    int row0 = I0 + RPL * w;
    int gj   = J0 + 2 * l;

    // [parity][top/bot][slot 0..9][lane]; wave w writes slot w+1;
    // reads up from slot w, down from slot w+2; slots 0,9 stay zero.
    __shared__ v2f hb[2][2][NW + 2][64];
    for (int k = t; k < 2 * 2 * (NW + 2) * 64; k += TPB)
        ((v2f*)hb)[k] = (v2f){0.f, 0.f};

    // source amplitudes for this chunk -> registers (compile-time indexed)
    float xv[TCH];
    int xbase = b * NSTEPS + chunk * TCH;
#pragma unroll
    for (int i = 0; i < TCH; i++) xv[i] = x[xbase + i];

    const float* kg = ws + K3_OFF;
    const float* qg = ws + Q_OFF;
    int pin = chunk & 1, pout = pin ^ 1;
    const float* curg  = ws + ((pin  * 2 + 0) * NBATCH + b) * CELLS;
    const float* prvg  = ws + ((pin  * 2 + 1) * NBATCH + b) * CELLS;
    float*       ncurg = ws + ((pout * 2 + 0) * NBATCH + b) * CELLS;
    float*       nprvg = ws + ((pout * 2 + 1) * NBATCH + b) * CELLS;

    // per-lane state: 4 v2f arrays x 3 rows = 24 VGPRs
    v2f yc[RPL], yp[RPL], Qa[RPL], Ka[RPL];
    bool cok = (gj >= 0 && gj < NXY);
#pragma unroll
    for (int r = 0; r < RPL; r++) {
        int gi = row0 + r;
        bool ok = cok && gi >= 0 && gi < NXY;
        v2f kv = {0.f,0.f}, qv = {0.f,0.f}, cv = {0.f,0.f}, pv = {0.f,0.f};
        if (ok) {
            int idx = gi * NXY + gj;
            kv = *(const v2f*)(kg + idx);
            qv = *(const v2f*)(qg + idx);
            cv = *(const v2f*)(curg + idx);
            pv = *(const v2f*)(prvg + idx);
        }
        yc[r] = cv; yp[r] = pv; Ka[r] = kv; Qa[r] = qv;
        // out-of-domain: K=Q=0 -> yn = c = 0 forever  ✓
    }

    // source (40,96): window col 96-J0 (112 for cj0 -> lane 56, 16 for cj1 -> lane 8)
    int sr = 40 - I0, sc = 96 - J0;
    bool wave_src = (sr >= RPL * w) && (sr < RPL * w + RPL);
    int src_rl = sr - RPL * w;
    float srcm = (2 * l == sc) ? 1.f : 0.f;

    // probes (160,{48,96,144}): row 160 -> bi==26, window row 13 (wave 4, r=1)
    int pcl = 2 * l + J0;             // this lane's global .x column
    bool wave_prb = (bi == 26) && (w == 4);
    const int prb_rl = 1;
    bool is_prb = (cj == 0) ? (pcl == 48) : (pcl == 96 || pcl == 144);
    float prbm = is_prb ? 1.f : 0.f;
    float pacc = 0.f;

    v2f uph, dnh;

// row update: yn = c + Q*(p-c) + K*(S-4c) — packed fp32, 2 DPP per 2 cells
#define ROWC(CUR, PRV, rr_, UP, DN, XSV, YN) do {                              \
    v2f cv = CUR[rr_];                                                         \
    float lf0 = dpp_up1(cv.y);                                                 \
    float rt1 = dpp_dn1(cv.x);                                                 \
    v2f h = (v2f){lf0, rt1} + __builtin_shufflevector(cv, cv, 1, 0);           \
    v2f S = ((UP) + (DN)) + h;                                                 \
    YN = cv + Qa[rr_] * (PRV[rr_] - cv) + Ka[rr_] * (S - 4.0f * cv);           \
    if (wave_src && (rr_) == src_rl) YN.x += srcm * (XSV);                     \
    if (wave_prb && (rr_) == prb_rl) { float q = prbm * YN.x; pacc += q * YN.x; } \
} while (0)

// boundary rows first (early LDS write), interior row hides it; ghost read
// after barrier is first used next step
#define STEP(CUR, PRV, PH, SIDX) do {                                          \
    v2f t0, t2;                                                                \
    ROWC(CUR, PRV, 0, uph,    CUR[1], xv[SIDX], t0);                           \
    ROWC(CUR, PRV, 2, CUR[1], dnh,    xv[SIDX], t2);                           \
    hb[PH][0][w + 1][l] = t0;                                                  \
    hb[PH][1][w + 1][l] = t2;                                                  \
    PRV[0] = t0; PRV[2] = t2;                                                  \
    {                                                                          \
        v2f y;                                                                 \
        ROWC(CUR, PRV, 1, CUR[0], CUR[2], xv[SIDX], y);                        \
        PRV[1] = y;                                                            \
    }                                                                          \
    __syncthreads();                                                           \
    uph = hb[PH][1][w][l];                                                     \
    dnh = hb[PH][0][w + 2][l];                                                 \
} while (0)

    // prologue halo exchange (parity 0)
    hb[0][0][w + 1][l] = yc[0];
    hb[0][1][w + 1][l] = yc[2];
    __syncthreads();
    uph = hb[0][1][w][l];
    dnh = hb[0][0][w + 2][l];

#pragma unroll
    for (int s2 = 0; s2 < TCH / 2; s2++) {
        STEP(yc, yp, 1, 2 * s2);        // new cur -> yp, writes hb[1]
        STEP(yp, yc, 0, 2 * s2 + 1);    // new cur -> yc, writes hb[0]
    }
#undef STEP
#undef ROWC
    // yc = y(t_end), yp = y(t_end-1); valid on window rows [8,16), cols [8,120)

    // store out-tile: rows [6bi, 6bi+6) (window rows [9,15)), lanes 8..55
#pragma unroll
    for (int r = 0; r < RPL; r++) {
        int gi = row0 + r;
        if (gi >= OUTR * bi && gi < OUTR * bi + OUTR && l >= 8 && l < 56) {
            int idx = gi * NXY + gj;
            *(v2f*)(ncurg + idx) = yc[r];
            *(v2f*)(nprvg + idx) = yp[r];
        }
    }
    // unique writer per (b,pid): bi==26, owning col-tile, one lane per probe
    if (wave_prb && is_prb)
        ws[I_OFF + b * 3 + (pcl / 48 - 1)] += pacc;
}

__global__ void final_k(const float* __restrict__ ws, float* __restrict__ out) {
    int t = threadIdx.x;
    if (t < 12) {
        const float* I = ws + I_OFF;
        int b = t / 3;
        float s = I[3 * b] + I[3 * b + 1] + I[3 * b + 2];
        out[t] = I[t] / s;
    }
}

extern "C" void kernel_launch(void* const* d_in, const int* in_sizes, int n_in,
                              void* d_out, int out_size, void* d_ws, size_t ws_size,
                              hipStream_t stream) {
    const float* x   = (const float*)d_in[0];   // (4,256) fp32
    const float* rho = (const float*)d_in[1];   // (192,192) fp32
    float* ws  = (float*)d_ws;
    float* out = (float*)d_out;

    setup_k<<<256, 256, 0, stream>>>(rho, ws);
    for (int c = 0; c < NCHUNK; c++)
        chunk_k<<<NBLKS, TPB, 0, stream>>>(x, ws, c);
    final_k<<<1, 64, 0, stream>>>(ws, out);
}

// Round 14
// 210.094 us; speedup vs baseline: 1.2075x; 1.2075x over previous
//
#include <hip/hip_runtime.h>
#include <math.h>

#define NXY    192
#define CELLS  (NXY*NXY)
#define NBATCH 4
#define NSTEPS 256
#define TCH    16                 // steps per chunk (= halo radius)
#define NCHUNK (NSTEPS/TCH)       // 16
#define TPB    512                // 8 waves -> 2 waves/SIMD
#define NW     8
#define RPL    5                  // rows per wave (40-row window / 8 waves)
#define OUTR   6                  // out rows per tile
#define NBLKS  256                // 32 row-tiles x 2 col-tiles x 4 batches
// in-tile 128 cols x 40 rows; out-tile 96 cols x 6 rows (window rows [17,23))

// workspace layout (float offsets)
#define K3_OFF (16*CELLS)
#define Q_OFF  (K3_OFF + CELLS)
#define I_OFF  (Q_OFF + CELLS)

typedef float v2f __attribute__((ext_vector_type(2)));

__device__ __forceinline__ float dpp_up1(float v) {   // lane i <- lane i-1
    int r = __builtin_amdgcn_update_dpp(0, __builtin_bit_cast(int, v),
                                        0x138, 0xf, 0xf, true); // wave_shr:1
    return __builtin_bit_cast(float, r);
}
__device__ __forceinline__ float dpp_dn1(float v) {   // lane i <- lane i+1
    int r = __builtin_amdgcn_update_dpp(0, __builtin_bit_cast(int, v),
                                        0x130, 0xf, 0xf, true); // wave_shl:1
    return __builtin_bit_cast(float, r);
}

__device__ __forceinline__ float pml_prof(int i) {
    int t;
    if (i <= 20)            t = 20 - i;
    else if (i >= NXY - 21) t = i - (NXY - 21);
    else                    return 0.0f;
    float u  = (float)t * 0.05f;
    float u2 = u * u;
    return 3.0f * u2 * u2;
}

__global__ void setup_k(const float* __restrict__ rho, float* __restrict__ ws) {
    int idx    = blockIdx.x * blockDim.x + threadIdx.x;
    int stride = gridDim.x * blockDim.x;
    for (int k = idx; k < 8 * CELLS; k += stride) ws[k] = 0.0f;  // parity-0 state
    const float IH2 = (float)(1.0 / (2.01 * 2.01));
    for (int k = idx; k < CELLS; k += stride) {
        int i = k / NXY, j = k % NXY;
        float r0 = rho[k];
        float ru = (i > 0)       ? rho[k - NXY] : 0.0f;
        float rd = (i < NXY - 1) ? rho[k + NXY] : 0.0f;
        float rl = (j > 0)       ? rho[k - 1]   : 0.0f;
        float rr2 = (j < NXY - 1) ? rho[k + 1]  : 0.0f;
        float lpf = 0.5f * r0 + 0.125f * ((ru + rd) + (rl + rr2));
        float p   = 0.5f * (1.0f + tanhf(100.0f * (lpf - 0.5f)));
        float c   = 1.0f - 0.1f * p;
        float c2h = c * c * IH2;
        float bx = pml_prof(i), by = pml_prof(j);
        float bb = sqrtf(bx * bx + by * by);
        float a1 = 1.0f / (1.0f + 0.5f * bb);
        ws[K3_OFF + k] = a1 * c2h;         // K
        ws[Q_OFF  + k] = 1.0f - 2.0f * a1; // Q
    }
    if (idx < 12) ws[I_OFF + idx] = 0.0f;
}

__global__ __launch_bounds__(TPB, 1)
void chunk_k(const float* __restrict__ x, float* __restrict__ ws, int chunk) {
    int blk = blockIdx.x;
    int b  = blk / 64;                // batch
    int r_ = blk % 64;
    int bi = r_ >> 1, cj = r_ & 1;    // 32 row-tiles x 2 col-tiles
    int I0 = OUTR * bi - 17;          // window row origin (40 rows)
    int J0 = 96 * cj - 16;            // window col origin (128 cols)
    int t  = threadIdx.x;
    int w  = t >> 6;                  // wave 0..7, owns window rows [5w,5w+5)
    int l  = t & 63;                  // lane: local cols 2l, 2l+1
    int row0 = I0 + RPL * w;
    int gj   = J0 + 2 * l;

    // [parity][top/bot][slot 0..9][lane]; wave w writes slot w+1;
    // reads up from slot w, down from slot w+2; slots 0,9 stay zero.
    __shared__ v2f hb[2][2][NW + 2][64];
    for (int k = t; k < 2 * 2 * (NW + 2) * 64; k += TPB)
        ((v2f*)hb)[k] = (v2f){0.f, 0.f};

    // source amplitudes for this chunk -> registers (compile-time indexed)
    float xv[TCH];
    int xbase = b * NSTEPS + chunk * TCH;
#pragma unroll
    for (int i = 0; i < TCH; i++) xv[i] = x[xbase + i];

    const float* kg = ws + K3_OFF;
    const float* qg = ws + Q_OFF;
    int pin = chunk & 1, pout = pin ^ 1;
    const float* curg  = ws + ((pin  * 2 + 0) * NBATCH + b) * CELLS;
    const float* prvg  = ws + ((pin  * 2 + 1) * NBATCH + b) * CELLS;
    float*       ncurg = ws + ((pout * 2 + 0) * NBATCH + b) * CELLS;
    float*       nprvg = ws + ((pout * 2 + 1) * NBATCH + b) * CELLS;

    // per-lane state: 4 v2f arrays x 5 rows = 40 VGPRs
    v2f yc[RPL], yp[RPL], Qa[RPL], Ka[RPL];
    bool cok = (gj >= 0 && gj < NXY);
#pragma unroll
    for (int r = 0; r < RPL; r++) {
        int gi = row0 + r;
        bool ok = cok && gi >= 0 && gi < NXY;
        v2f kv = {0.f,0.f}, qv = {0.f,0.f}, cv = {0.f,0.f}, pv = {0.f,0.f};
        if (ok) {
            int idx = gi * NXY + gj;
            kv = *(const v2f*)(kg + idx);
            qv = *(const v2f*)(qg + idx);
            cv = *(const v2f*)(curg + idx);
            pv = *(const v2f*)(prvg + idx);
        }
        yc[r] = cv; yp[r] = pv; Ka[r] = kv; Qa[r] = qv;
        // out-of-domain: K=Q=0 -> yn = c = 0 forever  ✓
    }

    // source (40,96): window col 96-J0 (112 for cj0 -> lane 56, 16 for cj1 -> lane 8)
    int sr = 40 - I0, sc = 96 - J0;
    bool wave_src = (sr >= RPL * w) && (sr < RPL * w + RPL);
    int src_rl = sr - RPL * w;
    float srcm = (2 * l == sc) ? 1.f : 0.f;

    // probes (160,{48,96,144}): row 160 -> bi==26, window row 21 (wave 4, r=1)
    int pcl = 2 * l + J0;             // this lane's global .x column
    bool wave_prb = (bi == 26) && (w == 4);
    const int prb_rl = 1;
    bool is_prb = (cj == 0) ? (pcl == 48) : (pcl == 96 || pcl == 144);
    float prbm = is_prb ? 1.f : 0.f;
    float pacc = 0.f;

    v2f uph, dnh;

// row update: yn = c + Q*(p-c) + K*(S-4c) — packed fp32, 2 DPP per 2 cells
#define ROWC(CUR, PRV, rr_, UP, DN, XSV, YN) do {                              \
    v2f cv = CUR[rr_];                                                         \
    float lf0 = dpp_up1(cv.y);                                                 \
    float rt1 = dpp_dn1(cv.x);                                                 \
    v2f h = (v2f){lf0, rt1} + __builtin_shufflevector(cv, cv, 1, 0);           \
    v2f S = ((UP) + (DN)) + h;                                                 \
    YN = cv + Qa[rr_] * (PRV[rr_] - cv) + Ka[rr_] * (S - 4.0f * cv);           \
    if (wave_src && (rr_) == src_rl) YN.x += srcm * (XSV);                     \
    if (wave_prb && (rr_) == prb_rl) { float q = prbm * YN.x; pacc += q * YN.x; } \
} while (0)

// INTERIOR-FIRST step: rows 1..3 use only own registers and issue while the
// post-barrier ghost ds_reads (uph/dnh) are still in flight; boundary rows
// 0/4 (first use of uph/dnh) come last, then write + barrier + next reads.
#define STEP(CUR, PRV, PH, SIDX) do {                                          \
    v2f y1, y2, y3, t0, t4;                                                    \
    ROWC(CUR, PRV, 1, CUR[0], CUR[2], xv[SIDX], y1);                           \
    ROWC(CUR, PRV, 2, CUR[1], CUR[3], xv[SIDX], y2);                           \
    ROWC(CUR, PRV, 3, CUR[2], CUR[4], xv[SIDX], y3);                           \
    ROWC(CUR, PRV, 0, uph,    CUR[1], xv[SIDX], t0);                           \
    ROWC(CUR, PRV, 4, CUR[3], dnh,    xv[SIDX], t4);                           \
    hb[PH][0][w + 1][l] = t0;                                                  \
    hb[PH][1][w + 1][l] = t4;                                                  \
    PRV[0] = t0; PRV[1] = y1; PRV[2] = y2; PRV[3] = y3; PRV[4] = t4;           \
    __syncthreads();                                                           \
    uph = hb[PH][1][w][l];                                                     \
    dnh = hb[PH][0][w + 2][l];                                                 \
} while (0)

    // prologue halo exchange (parity 0)
    hb[0][0][w + 1][l] = yc[0];
    hb[0][1][w + 1][l] = yc[4];
    __syncthreads();
    uph = hb[0][1][w][l];
    dnh = hb[0][0][w + 2][l];

#pragma unroll
    for (int s2 = 0; s2 < TCH / 2; s2++) {
        STEP(yc, yp, 1, 2 * s2);        // new cur -> yp, writes hb[1]
        STEP(yp, yc, 0, 2 * s2 + 1);    // new cur -> yc, writes hb[0]
    }
#undef STEP
#undef ROWC
    // yc = y(t_end), yp = y(t_end-1); clean on window rows [16,24), cols [16,112)

    // store out-tile: rows [6bi, 6bi+6) (window rows [17,23)), lanes 8..55
#pragma unroll
    for (int r = 0; r < RPL; r++) {
        int gi = row0 + r;
        if (gi >= OUTR * bi && gi < OUTR * bi + OUTR && l >= 8 && l < 56) {
            int idx = gi * NXY + gj;
            *(v2f*)(ncurg + idx) = yc[r];
            *(v2f*)(nprvg + idx) = yp[r];
        }
    }
    // unique writer per (b,pid): bi==26, owning col-tile, one lane per probe
    if (wave_prb && is_prb)
        ws[I_OFF + b * 3 + (pcl / 48 - 1)] += pacc;
}

__global__ void final_k(const float* __restrict__ ws, float* __restrict__ out) {
    int t = threadIdx.x;
    if (t < 12) {
        const float* I = ws + I_OFF;
        int b = t / 3;
        float s = I[3 * b] + I[3 * b + 1] + I[3 * b + 2];
        out[t] = I[t] / s;
    }
}

extern "C" void kernel_launch(void* const* d_in, const int* in_sizes, int n_in,
                              void* d_out, int out_size, void* d_ws, size_t ws_size,
                              hipStream_t stream) {
    const float* x   = (const float*)d_in[0];   // (4,256) fp32
    const float* rho = (const float*)d_in[1];   // (192,192) fp32
    float* ws  = (float*)d_ws;
    float* out = (float*)d_out;

    setup_k<<<256, 256, 0, stream>>>(rho, ws);
    for (int c = 0; c < NCHUNK; c++)
        chunk_k<<<NBLKS, TPB, 0, stream>>>(x, ws, c);
    final_k<<<1, 64, 0, stream>>>(ws, out);
}